// Round 1
// baseline (81.810 us; speedup 1.0000x reference)
//
#include <hip/hip_runtime.h>
#include <stdint.h>

// ---------------------------------------------------------------------------
// quantized_conv: bit-serial IMC conv simulation, exact integer path via i8 MFMA
//
// Math: out[b,o,p] = (norm/255) * sum_{c,s,t} 4^(s+t) *
//          ( min(31, sum_f a_s[f] * wp_t[f]) - min(31, sum_f a_s[f] * wn_t[f]) )
// where a_s = 2-bit digit s of the 8-bit two's-complement quantized input patch,
// wp_t/wn_t = 2-bit digit t of round(|w|+-/max|w|*255). All digits in 0..3, so the
// per-chunk dots (K=116) are exact in i32 -> bit-exact vs the fp32 reference.
// ---------------------------------------------------------------------------

typedef int v4i __attribute__((ext_vector_type(4)));
typedef unsigned int v4u __attribute__((ext_vector_type(4)));

// workspace layout (bytes)
#define WS_NORM   0         // 4 bytes: max|w| as float bits (atomicMax on uint)
#define WS_QIMG   1024      // 262144 bytes: quantized input image bytes [b][ic][y][x]
#define WS_AQ     263168    // 4096*640 bytes: unfolded patch bytes [m][k], k = c*128+j
#define WS_BP     2884608   // 5*2*64*64 = 40960 bytes: [c][kblk][o][k64] pos weight bytes
#define WS_BN     2925568   // 40960 bytes: neg weight bytes
#define WS_TOTAL  2966528

// ---------------------------------------------------------------------------
// prep1: quantize input image to bytes; reduce max|w|; write scalar output 0.0
// grid: 1024 blocks input quant + 144 blocks weight max  (256 thr)
// ---------------------------------------------------------------------------
__global__ __launch_bounds__(256) void k_prep1(
    const float* __restrict__ in, const float* __restrict__ w,
    unsigned char* __restrict__ qimg, unsigned int* __restrict__ nrm,
    float* __restrict__ out_scalar)
{
  int bid = blockIdx.x, tid = threadIdx.x;
  if (bid == 0 && tid == 0) out_scalar[0] = 0.0f;  // second tuple output
  if (bid < 1024) {
    int idx = bid * 256 + tid;                      // [0, 262144)
    float x = in[idx];
    x = fminf(fmaxf(x, -8.0f), 7.9375f);            // clip to fixed-point range
    int q = (int)rintf(x * 16.0f);                  // round-half-even like jnp.round
    qimg[idx] = (unsigned char)(q & 255);           // two's complement byte
  } else {
    int idx = (bid - 1024) * 256 + tid;             // [0, 36864)
    float a = fabsf(w[idx]);
    #pragma unroll
    for (int off = 32; off > 0; off >>= 1)
      a = fmaxf(a, __shfl_down(a, off, 64));
    if ((tid & 63) == 0)
      atomicMax(nrm, __float_as_uint(a));           // a>=0 -> bits monotonic
  }
}

// ---------------------------------------------------------------------------
// prep2: build weight slice-byte matrices (needs norm) + im2col byte unfold
// grid: 160 blocks weights + 2560 blocks unfold (256 thr)
// ---------------------------------------------------------------------------
__global__ __launch_bounds__(256) void k_prep2(
    const float* __restrict__ w, const unsigned char* __restrict__ qimg,
    const unsigned int* __restrict__ nrmu,
    unsigned char* __restrict__ Aq, unsigned char* __restrict__ Bp,
    unsigned char* __restrict__ Bn)
{
  int bid = blockIdx.x, tid = threadIdx.x;
  if (bid < 160) {
    float norm = __uint_as_float(*nrmu);
    if (!(norm > 0.0f)) norm = 1.0f;
    int idx = bid * 256 + tid;          // [0, 40960) = [c][o][k<128]
    int c   = idx >> 13;
    int rem = idx & 8191;
    int o   = rem >> 7;
    int k   = rem & 127;
    int csize = (c == 4) ? 112 : 116;   // last chunk has 4 zero-pad features
    unsigned char pb = 0, nb = 0;
    if (k < csize) {
      float wv = w[o * 576 + c * 116 + k];   // f = ic*9+kh*3+kw ordering
      float wp = fmaxf(wv, 0.0f);
      float wn = fmaxf(-wv, 0.0f);
      pb = (unsigned char)(int)rintf(wp / norm * 255.0f);  // all 4 slices live in this byte
      nb = (unsigned char)(int)rintf(wn / norm * 255.0f);
    }
    int addr = (c * 2 + (k >> 6)) * 4096 + o * 64 + (k & 63);
    Bp[addr] = pb;
    Bn[addr] = nb;
  } else {
    int widx = (bid - 160) * 256 + tid;  // word index [0, 655360): m*160 + kw
    int m  = widx / 160;
    int kw = widx - m * 160;
    int b = m >> 10, p = m & 1023;
    int y = p >> 5, x = p & 31;
    unsigned int pack = 0;
    #pragma unroll
    for (int i = 0; i < 4; ++i) {
      int k = kw * 4 + i;
      int c = k >> 7;
      int j = k & 127;
      int csize = (c == 4) ? 112 : 116;
      unsigned int bv = 0;
      if (j < csize) {
        int f  = c * 116 + j;
        int ic = f / 9;
        int r9 = f - ic * 9;
        int kh = r9 / 3;
        int k2 = r9 - kh * 3;
        int iy = y + kh - 1, ix = x + k2 - 1;
        if (iy >= 0 && iy < 32 && ix >= 0 && ix < 32)
          bv = qimg[((b * 64 + ic) * 32 + iy) * 32 + ix];
      }
      pack |= bv << (8 * i);
    }
    ((unsigned int*)Aq)[widx] = pack;
  }
}

// extract 2-bit field s of each byte in a packed dword vector
__device__ __forceinline__ v4i bits2(v4u w, int s) {
  v4u r = (w >> (unsigned)(2 * s)) & 0x03030303u;
  return (v4i)r;
}

// ---------------------------------------------------------------------------
// main: per wave 16m x 16o output tile; loop chunks c, streams s, slices t,
// signs; 2 k-steps of mfma_i32_16x16x64_i8 per chunk; ADC clip + 4^(s+t) fold
// grid: 256 blocks (64 mtiles x 4 otiles), 256 thr = 4 waves (wave = 16 m rows)
// ---------------------------------------------------------------------------
__global__ __launch_bounds__(256) void k_main(
    const unsigned char* __restrict__ Aq,
    const unsigned char* __restrict__ Bp,
    const unsigned char* __restrict__ Bn,
    const unsigned int* __restrict__ nrmu,
    float* __restrict__ out)
{
  int lane  = threadIdx.x & 63;
  int wave  = threadIdx.x >> 6;
  int mtile = blockIdx.x >> 2;
  int otile = blockIdx.x & 3;
  int r16  = lane & 15;
  int kgrp = lane >> 4;                 // A: m=lane&15, k=kgrp*16+j ; B: n=lane&15
  int m = mtile * 64 + wave * 16 + r16;
  int o = otile * 16 + r16;

  const unsigned char* ap  = Aq + m * 640 + kgrp * 16;
  const unsigned char* bpp = Bp + o * 64 + kgrp * 16;
  const unsigned char* bnp = Bn + o * 64 + kgrp * 16;

  v4i outacc = {0, 0, 0, 0};

  #pragma unroll
  for (int c = 0; c < 5; ++c) {
    v4u a0 = *(const v4u*)(ap + c * 128);        // packed input bytes, kblk 0
    v4u a1 = *(const v4u*)(ap + c * 128 + 64);   // kblk 1
    v4u p0 = *(const v4u*)(bpp + (c * 2 + 0) * 4096);
    v4u p1 = *(const v4u*)(bpp + (c * 2 + 1) * 4096);
    v4u n0 = *(const v4u*)(bnp + (c * 2 + 0) * 4096);
    v4u n1 = *(const v4u*)(bnp + (c * 2 + 1) * 4096);

    // extract the 4 slice fragments once per chunk (reused across all 4 streams)
    v4i btp0[4], btp1[4], btn0[4], btn1[4];
    #pragma unroll
    for (int t = 0; t < 4; ++t) {
      btp0[t] = bits2(p0, t); btp1[t] = bits2(p1, t);
      btn0[t] = bits2(n0, t); btn1[t] = bits2(n1, t);
    }

    #pragma unroll
    for (int s = 0; s < 4; ++s) {
      v4i as0 = bits2(a0, s), as1 = bits2(a1, s);
      #pragma unroll
      for (int t = 0; t < 4; ++t) {
        v4i z = {0, 0, 0, 0};
        v4i pacc = __builtin_amdgcn_mfma_i32_16x16x64_i8(as0, btp0[t], z, 0, 0, 0);
        pacc     = __builtin_amdgcn_mfma_i32_16x16x64_i8(as1, btp1[t], pacc, 0, 0, 0);
        v4i nacc = __builtin_amdgcn_mfma_i32_16x16x64_i8(as0, btn0[t], z, 0, 0, 0);
        nacc     = __builtin_amdgcn_mfma_i32_16x16x64_i8(as1, btn1[t], nacc, 0, 0, 0);
        int sh = 2 * (s + t);
        #pragma unroll
        for (int r = 0; r < 4; ++r) {
          // ADC: values are >=0 integers; clip(round(x),0,31) == min(x,31)
          int d = (pacc[r] < 31 ? pacc[r] : 31) - (nacc[r] < 31 ? nacc[r] : 31);
          outacc[r] += d << sh;   // |outacc| <= 31*85*85*5 ~ 1.12e6, exact in i32/f32
        }
      }
    }
  }

  float norm = __uint_as_float(*nrmu);
  if (!(norm > 0.0f)) norm = 1.0f;
  // C/D layout: col(n=o) = lane&15, row(m) = (lane>>4)*4 + r
  int oc = otile * 16 + r16;
  #pragma unroll
  for (int r = 0; r < 4; ++r) {
    int mo = mtile * 64 + wave * 16 + kgrp * 4 + r;
    int b = mo >> 10, p = mo & 1023;
    out[(b * 64 + oc) * 1024 + p] = ((float)outacc[r] * norm) / 255.0f;
  }
}

extern "C" void kernel_launch(void* const* d_in, const int* in_sizes, int n_in,
                              void* d_out, int out_size, void* d_ws, size_t ws_size,
                              hipStream_t stream) {
  const float* inp = (const float*)d_in[0];   // (4,64,32,32) f32
  const float* wgt = (const float*)d_in[1];   // (64,64,3,3)  f32
  float* out = (float*)d_out;                 // 262144 + 1 f32
  unsigned char* ws = (unsigned char*)d_ws;

  unsigned int*  nrm  = (unsigned int*)(ws + WS_NORM);
  unsigned char* qimg = ws + WS_QIMG;
  unsigned char* Aq   = ws + WS_AQ;
  unsigned char* Bp   = ws + WS_BP;
  unsigned char* Bn   = ws + WS_BN;

  hipMemsetAsync(nrm, 0, 4, stream);          // atomicMax identity (ws is poisoned)
  k_prep1<<<1168, 256, 0, stream>>>(inp, wgt, qimg, nrm, out + 262144);
  k_prep2<<<2720, 256, 0, stream>>>(wgt, qimg, nrm, Aq, Bp, Bn);
  k_main <<<256, 256, 0, stream>>>(Aq, Bp, Bn, nrm, out);
}

// Round 2
// 79.575 us; speedup vs baseline: 1.0281x; 1.0281x over previous
//
#include <hip/hip_runtime.h>
#include <stdint.h>

// ---------------------------------------------------------------------------
// quantized_conv: bit-serial IMC conv simulation, exact integer path via i8 MFMA
//
// out[b,o,p] = (norm/255) * sum_{c,s,t} 4^(s+t) *
//    ( min(31, sum_f a_s[f]*wp_t[f]) - min(31, sum_f a_s[f]*wn_t[f]) )
// a_s = 2-bit digit s of the 8-bit two's-complement quantized input patch;
// wp_t/wn_t = 2-bit digit t of round(|w|+-/max|w|*255). Digits in 0..3 ->
// per-chunk K=116 dots exact in i32 -> bit-exact vs fp32 reference (R1: absmax=0).
//
// R2 restructure: 5 graph nodes -> 2. Unfold quantizes floats on the fly
// (no qimg pass); weight max via per-wave partials (no atomics/memset);
// weight quantization folded into main kernel (per-block LDS tile).
// ---------------------------------------------------------------------------

typedef int v4i __attribute__((ext_vector_type(4)));
typedef unsigned int v4u __attribute__((ext_vector_type(4)));

// workspace layout (bytes)
#define WS_PART   0          // 144 floats: per-wave |w| max partials
#define WS_AQ     1024       // 4096*640 bytes: unfolded patch bytes [m][k], k=c*128+j
#define N_PART    144

__device__ __forceinline__ unsigned char quant_in(float x) {
  x = fminf(fmaxf(x, -8.0f), 7.9375f);     // fixed-point clip (int_bits=3, frac=4)
  int q = (int)rintf(x * 16.0f);           // round-half-even == jnp.round
  return (unsigned char)(q & 255);         // two's complement byte
}

// ---------------------------------------------------------------------------
// k_prep: im2col byte unfold (quantize floats on the fly) + weight max partials
// grid: 2560 unfold blocks + 36 weight blocks, 256 thr
// ---------------------------------------------------------------------------
__global__ __launch_bounds__(256) void k_prep(
    const float* __restrict__ in, const float* __restrict__ w,
    unsigned char* __restrict__ Aq, float* __restrict__ part,
    float* __restrict__ out_scalar)
{
  int bid = blockIdx.x, tid = threadIdx.x;
  if (bid == 0 && tid == 0) out_scalar[0] = 0.0f;   // second tuple output
  if (bid < 2560) {
    unsigned int widx = bid * 256 + tid;            // dword index: m*160 + kw
    unsigned int m  = ((widx >> 5) * 52429u) >> 18; // widx/160
    unsigned int kw = widx - m * 160;
    int b = m >> 10, p = m & 1023;
    int y = p >> 5, x = p & 31;
    unsigned int pack = 0;
    #pragma unroll
    for (int i = 0; i < 4; ++i) {
      unsigned int k = kw * 4 + i;
      unsigned int c = k >> 7;
      unsigned int j = k & 127;
      unsigned int csize = (c == 4) ? 112 : 116;
      unsigned int bv = 0;
      if (j < csize) {
        unsigned int f  = c * 116 + j;              // f = ic*9 + dy*3 + dx
        unsigned int ic = (f * 7282u) >> 16;        // f/9  (f<576)
        unsigned int r9 = f - ic * 9;
        unsigned int dy = (r9 * 11u) >> 5;          // r9/3
        unsigned int dx = r9 - dy * 3;
        int iy = y + (int)dy - 1, ix = x + (int)dx - 1;
        if (iy >= 0 && iy < 32 && ix >= 0 && ix < 32)
          bv = quant_in(in[((b * 64 + ic) * 32 + iy) * 32 + ix]);
      }
      pack |= bv << (8 * i);
    }
    ((unsigned int*)Aq)[widx] = pack;
  } else {
    int t = (bid - 2560) * 256 + tid;               // [0, 9216)
    const float4 wv = ((const float4*)w)[t];        // 4 consecutive weights
    float a = fmaxf(fmaxf(fabsf(wv.x), fabsf(wv.y)),
                    fmaxf(fabsf(wv.z), fabsf(wv.w)));
    #pragma unroll
    for (int off = 32; off > 0; off >>= 1)
      a = fmaxf(a, __shfl_down(a, off, 64));
    if ((tid & 63) == 0)
      part[(bid - 2560) * 4 + (tid >> 6)] = a;      // 144 partials
  }
}

// extract 2-bit field s of each byte in a packed dword vector
__device__ __forceinline__ v4i bits2(v4u w, int s) {
  v4u r = (w >> (unsigned)(2 * s)) & 0x03030303u;
  return (v4i)r;
}

#define BROW 656   // LDS row stride for B tiles (164 dwords == 4 mod 32 banks)

// ---------------------------------------------------------------------------
// k_main: norm finalize + per-block weight quant into LDS + MFMA/clip/fold
// grid: 256 blocks (64 mtiles x 4 otiles), 256 thr = 4 waves (16m x 16o each)
// ---------------------------------------------------------------------------
__global__ __launch_bounds__(256) void k_main(
    const unsigned char* __restrict__ Aq, const float* __restrict__ w,
    const float* __restrict__ part, float* __restrict__ out)
{
  __shared__ unsigned char Bl[2][16][BROW];   // [sign][o_local][kpos], 20992 B
  __shared__ float s_norm;

  int tid   = threadIdx.x;
  int lane  = tid & 63;
  int wave  = tid >> 6;
  int mtile = blockIdx.x >> 2;
  int otile = blockIdx.x & 3;

  // ---- zero LDS B (covers chunk zero-pad regions) + norm reduce (wave 0) ----
  #pragma unroll
  for (int i = 0; i < 21; ++i) {
    int d = i * 256 + tid;                    // 5248 dwords total
    if (d < 2 * 16 * BROW / 4) ((unsigned int*)Bl)[d] = 0u;
  }
  if (wave == 0) {
    float a = part[lane];                                   // 144 partials
    a = fmaxf(a, part[lane + 64]);
    if (lane < 16) a = fmaxf(a, part[lane + 128]);
    #pragma unroll
    for (int off = 32; off > 0; off >>= 1)
      a = fmaxf(a, __shfl_down(a, off, 64));
    if (lane == 0) s_norm = (a > 0.0f) ? a : 1.0f;
  }
  __syncthreads();

  // ---- quantize this otile's weights into LDS ----
  float norm = s_norm;
  float sc = 255.0f / norm;
  #pragma unroll
  for (int it = 0; it < 36; ++it) {
    int idx = it * 256 + tid;                 // [0, 9216) = 16 o x 576 f
    unsigned int ol = (((unsigned)idx >> 6) * 7282u) >> 16;  // idx/576
    unsigned int f  = idx - ol * 576;
    float wv = w[(otile * 16 + ol) * 576 + f];
    unsigned int c = (f * 565u) >> 16;        // f/116
    unsigned int j = f - c * 116;
    int kpos = c * 128 + j;
    Bl[0][ol][kpos] = (unsigned char)(int)rintf(fmaxf(wv, 0.0f) * sc);
    Bl[1][ol][kpos] = (unsigned char)(int)rintf(fmaxf(-wv, 0.0f) * sc);
  }
  __syncthreads();

  // ---- MFMA main loop ----
  int r16  = lane & 15;
  int kgrp = lane >> 4;                 // A: m=lane&15,k=kgrp*16+j ; B: n=lane&15
  int m = mtile * 64 + wave * 16 + r16;
  const unsigned char* ap = Aq + m * 640 + kgrp * 16;
  const unsigned char* bp = &Bl[0][r16][kgrp * 16];
  const unsigned char* bn = &Bl[1][r16][kgrp * 16];

  v4i outacc = {0, 0, 0, 0};

  #pragma unroll
  for (int c = 0; c < 5; ++c) {
    v4u a0 = *(const v4u*)(ap + c * 128);
    v4u a1 = *(const v4u*)(ap + c * 128 + 64);
    v4u p0 = *(const v4u*)(bp + c * 128);
    v4u p1 = *(const v4u*)(bp + c * 128 + 64);
    v4u n0 = *(const v4u*)(bn + c * 128);
    v4u n1 = *(const v4u*)(bn + c * 128 + 64);

    v4i btp0[4], btp1[4], btn0[4], btn1[4];
    #pragma unroll
    for (int t = 0; t < 4; ++t) {
      btp0[t] = bits2(p0, t); btp1[t] = bits2(p1, t);
      btn0[t] = bits2(n0, t); btn1[t] = bits2(n1, t);
    }

    #pragma unroll
    for (int s = 0; s < 4; ++s) {
      v4i as0 = bits2(a0, s), as1 = bits2(a1, s);
      #pragma unroll
      for (int t = 0; t < 4; ++t) {
        v4i z = {0, 0, 0, 0};
        v4i pacc = __builtin_amdgcn_mfma_i32_16x16x64_i8(as0, btp0[t], z, 0, 0, 0);
        pacc     = __builtin_amdgcn_mfma_i32_16x16x64_i8(as1, btp1[t], pacc, 0, 0, 0);
        v4i nacc = __builtin_amdgcn_mfma_i32_16x16x64_i8(as0, btn0[t], z, 0, 0, 0);
        nacc     = __builtin_amdgcn_mfma_i32_16x16x64_i8(as1, btn1[t], nacc, 0, 0, 0);
        int sh = 2 * (s + t);
        #pragma unroll
        for (int r = 0; r < 4; ++r) {
          int d = (pacc[r] < 31 ? pacc[r] : 31) - (nacc[r] < 31 ? nacc[r] : 31);
          outacc[r] += d << sh;   // |outacc| <= 31*85*85*5 ~ 1.12e6, exact
        }
      }
    }
  }

  // C/D layout: col(n=o) = lane&15, row(m) = (lane>>4)*4 + r
  float fsc = norm / 255.0f;
  int oc = otile * 16 + r16;
  #pragma unroll
  for (int r = 0; r < 4; ++r) {
    int mo = mtile * 64 + wave * 16 + kgrp * 4 + r;
    int b = mo >> 10, p = mo & 1023;
    out[(b * 64 + oc) * 1024 + p] = (float)outacc[r] * fsc;
  }
}

extern "C" void kernel_launch(void* const* d_in, const int* in_sizes, int n_in,
                              void* d_out, int out_size, void* d_ws, size_t ws_size,
                              hipStream_t stream) {
  const float* inp = (const float*)d_in[0];   // (4,64,32,32) f32
  const float* wgt = (const float*)d_in[1];   // (64,64,3,3)  f32
  float* out = (float*)d_out;                 // 262144 + 1 f32
  unsigned char* ws = (unsigned char*)d_ws;

  float*         part = (float*)(ws + WS_PART);
  unsigned char* Aq   = ws + WS_AQ;

  k_prep<<<2596, 256, 0, stream>>>(inp, wgt, Aq, part, out + 262144);
  k_main<<<256, 256, 0, stream>>>(Aq, wgt, part, out);
}